// Round 9
// baseline (229.437 us; speedup 1.0000x reference)
//
#include <hip/hip_runtime.h>
#include <cstdint>

// Shapes (fixed by the problem): B=2, C=64, G=4 -> CG=256, DQK=8, L=64*64=4096
constexpr int Bc  = 2;
constexpr int CGc = 256;
constexpr int Dc  = 8;
constexpr int Lc  = 4096;

typedef __attribute__((ext_vector_type(8)))  short short8;
typedef __attribute__((ext_vector_type(4)))  float floatx4;
typedef __attribute__((ext_vector_type(16))) float floatx16;

__device__ inline unsigned short f2bf(float f) {
  union { float f; unsigned u; } v; v.f = f;
  unsigned r = v.u + 0x7fffu + ((v.u >> 16) & 1u);
  return (unsigned short)(r >> 16);
}
__device__ inline float bf2f(unsigned short h) {
  return __uint_as_float((unsigned)h << 16);
}

// ---------------------------------------------------------------------------
// Phase -1: zero Mrow(8192) + Ssum(8192) — contiguous 16384 floats.
// ---------------------------------------------------------------------------
__global__ __launch_bounds__(256) void init_stats(float* __restrict__ p) {
  p[blockIdx.x * 256 + threadIdx.x] = 0.f;
}

// ---------------------------------------------------------------------------
// Phase 0: Wcat[cc][k] bf16 = [[Wr, -Wi], [Wi, Wr]] (512x512) for v_gemm.
// ---------------------------------------------------------------------------
__global__ __launch_bounds__(256) void wcat_pack(const float* __restrict__ wv,
                                                 unsigned short* __restrict__ Wcat) {
  const int i  = blockIdx.x * 256 + threadIdx.x;  // 0..262143
  const int cc = i >> 9, k = i & 511;
  const int co = cc >> 8, c = cc & 255, ci = k >> 8, cin = k & 255;
  const float wr = wv[(size_t)c * CGc + cin];
  const float wi = wv[(size_t)(CGc + c) * CGc + cin];
  const float val = co == 0 ? (ci == 0 ? wr : -wi) : (ci == 0 ? wi : wr);
  Wcat[i] = f2bf(val);
}

// ---------------------------------------------------------------------------
// Phase 0b: LDS-transpose x -> Xlk[b][l][cin2] bf16 (cin2 = comp*256+cin).
// ---------------------------------------------------------------------------
__global__ __launch_bounds__(256) void xT_pack(const float* __restrict__ x,
                                               unsigned short* __restrict__ Xlk) {
  __shared__ float xs[64][65];
  const int tid = threadIdx.x;
  const int b   = blockIdx.z;
  const int l0  = blockIdx.x * 64;
  const int c0  = blockIdx.y * 64;
  const int lt  = tid & 63, r4 = tid >> 6;
#pragma unroll
  for (int p = 0; p < 16; ++p) {
    const int row  = p * 4 + r4;
    const int cin2 = c0 + row;
    const int comp = cin2 >> 8, cin = cin2 & 255;
    xs[row][lt] = x[((size_t)(comp * Bc + b) * CGc + cin) * Lc + l0 + lt];
  }
  __syncthreads();
#pragma unroll
  for (int p = 0; p < 16; ++p) {
    const int lr = p * 4 + r4;
    Xlk[((size_t)b * Lc + l0 + lr) * 512 + c0 + lt] = f2bf(xs[lt][lr]);
  }
}

// ---------------------------------------------------------------------------
// Phase 1: complex Q AND K projections in one pass (x read once, fp32).
// ---------------------------------------------------------------------------
__global__ __launch_bounds__(256) void qk_proj(const float* __restrict__ x,
                                               const float* __restrict__ wq,
                                               const float* __restrict__ wk,
                                               float* __restrict__ qout,
                                               float* __restrict__ kout) {
  __shared__ float ws[4 * Dc * CGc];  // 32 KB: wq_r | wq_i | wk_r | wk_i
  const int tid = threadIdx.x;
  const int b   = blockIdx.y;
  for (int i = tid; i < 2 * Dc * CGc; i += 256) {
    ws[i]                 = wq[i];
    ws[2 * Dc * CGc + i]  = wk[i];
  }
  __syncthreads();
  const int d  = tid >> 5;   // 0..7
  const int ml = tid & 31;   // 0..31
  const int m  = blockIdx.x * 32 + ml;
  const float* xr = x + ((size_t)(0 * Bc + b) * CGc) * Lc + m;
  const float* xi = x + ((size_t)(1 * Bc + b) * CGc) * Lc + m;
  const float* wqr = ws + d * CGc;
  const float* wqi = ws + (Dc + d) * CGc;
  const float* wkr = ws + 2 * Dc * CGc + d * CGc;
  const float* wki = ws + 2 * Dc * CGc + (Dc + d) * CGc;
  float qer = 0.f, qei = 0.f, ker = 0.f, kei = 0.f;
#pragma unroll 4
  for (int cin = 0; cin < CGc; ++cin) {
    const float vr = xr[(size_t)cin * Lc];
    const float vi = xi[(size_t)cin * Lc];
    const float a1 = wqr[cin], b1 = wqi[cin];
    qer = fmaf(a1, vr, qer); qer = fmaf(-b1, vi, qer);
    qei = fmaf(a1, vi, qei); qei = fmaf(b1, vr, qei);
    const float a2 = wkr[cin], b2 = wki[cin];
    ker = fmaf(a2, vr, ker); ker = fmaf(-b2, vi, ker);
    kei = fmaf(a2, vi, kei); kei = fmaf(b2, vr, kei);
  }
  float* qp = qout + ((size_t)b * Lc + m) * 16;
  qp[d]     = qer;
  qp[8 + d] = qei;
  float* kp = kout + ((size_t)b * Lc + m) * 16;
  kp[d]     = ker;
  kp[8 + d] = kei;
}

// ---------------------------------------------------------------------------
// Phase 1b: split-bf16 packing for MFMA QK^T.
// ---------------------------------------------------------------------------
__global__ __launch_bounds__(256) void qk_pack(const float* __restrict__ q,
                                               const float* __restrict__ k,
                                               unsigned short* __restrict__ Qcat,
                                               unsigned short* __restrict__ K1hi,
                                               unsigned short* __restrict__ K1lo,
                                               unsigned short* __restrict__ K2hi,
                                               unsigned short* __restrict__ K2lo) {
  const int r = blockIdx.x * 256 + threadIdx.x;  // 0..8191
  {
    const float* qp = q + (size_t)r * 16;
    unsigned u[16];
#pragma unroll
    for (int t = 0; t < 8; ++t) {
      const float v0 = qp[2 * t], v1 = qp[2 * t + 1];
      const unsigned short h0 = f2bf(v0), h1 = f2bf(v1);
      u[t] = (unsigned)h0 | ((unsigned)h1 << 16);
      const unsigned short l0 = f2bf(v0 - bf2f(h0));
      const unsigned short l1 = f2bf(v1 - bf2f(h1));
      u[8 + t] = (unsigned)l0 | ((unsigned)l1 << 16);
    }
    uint4* dst = (uint4*)(Qcat + (size_t)r * 32);
    dst[0] = make_uint4(u[0], u[1], u[2], u[3]);
    dst[1] = make_uint4(u[4], u[5], u[6], u[7]);
    dst[2] = make_uint4(u[8], u[9], u[10], u[11]);
    dst[3] = make_uint4(u[12], u[13], u[14], u[15]);
  }
  {
    const float* kp = k + (size_t)r * 16;
    float k1[16], k2[16];
#pragma unroll
    for (int d = 0; d < 8; ++d) {
      const float kr = kp[d], ki = kp[8 + d];
      k1[d] = kr;  k1[8 + d] = -ki;
      k2[d] = ki;  k2[8 + d] = kr;
    }
    unsigned uh[8], ul[8];
#pragma unroll
    for (int t = 0; t < 8; ++t) {
      const unsigned short h0 = f2bf(k1[2 * t]), h1 = f2bf(k1[2 * t + 1]);
      uh[t] = (unsigned)h0 | ((unsigned)h1 << 16);
      const unsigned short l0 = f2bf(k1[2 * t] - bf2f(h0));
      const unsigned short l1 = f2bf(k1[2 * t + 1] - bf2f(h1));
      ul[t] = (unsigned)l0 | ((unsigned)l1 << 16);
    }
    uint4* dh = (uint4*)(K1hi + (size_t)r * 16);
    dh[0] = make_uint4(uh[0], uh[1], uh[2], uh[3]);
    dh[1] = make_uint4(uh[4], uh[5], uh[6], uh[7]);
    uint4* dl = (uint4*)(K1lo + (size_t)r * 16);
    dl[0] = make_uint4(ul[0], ul[1], ul[2], ul[3]);
    dl[1] = make_uint4(ul[4], ul[5], ul[6], ul[7]);
#pragma unroll
    for (int t = 0; t < 8; ++t) {
      const unsigned short h0 = f2bf(k2[2 * t]), h1 = f2bf(k2[2 * t + 1]);
      uh[t] = (unsigned)h0 | ((unsigned)h1 << 16);
      const unsigned short l0 = f2bf(k2[2 * t] - bf2f(h0));
      const unsigned short l1 = f2bf(k2[2 * t + 1] - bf2f(h1));
      ul[t] = (unsigned)l0 | ((unsigned)l1 << 16);
    }
    uint4* dh2 = (uint4*)(K2hi + (size_t)r * 16);
    dh2[0] = make_uint4(uh[0], uh[1], uh[2], uh[3]);
    dh2[1] = make_uint4(uh[4], uh[5], uh[6], uh[7]);
    uint4* dl2 = (uint4*)(K2lo + (size_t)r * 16);
    dl2[0] = make_uint4(ul[0], ul[1], ul[2], ul[3]);
    dl2[1] = make_uint4(ul[4], ul[5], ul[6], ul[7]);
  }
}

// ---------------------------------------------------------------------------
// Phase 2: V projection GEMM, 32x32x16 MFMA, 128x128 tile, dbuf single-barrier.
// v[cc][l] = sum_k Wcat[cc][k] * Xlk[l][k], K=512.
// ---------------------------------------------------------------------------
__global__ __launch_bounds__(256) void v_gemm(const unsigned short* __restrict__ Wcat,
                                              const unsigned short* __restrict__ Xlk,
                                              unsigned short* __restrict__ vbf) {
  __shared__ short As[2][128 * 64];
  __shared__ short Bs[2][128 * 64];
  const int tid  = threadIdx.x;
  const int b    = blockIdx.z;
  const int cc0  = blockIdx.x * 128;
  const int l0   = blockIdx.y * 128;
  const int wid  = tid >> 6, lane = tid & 63;
  const int wcc  = (wid >> 1) * 64;
  const int wl   = (wid & 1) * 64;
  const int l31  = lane & 31, khalf = lane >> 5;
  floatx16 acc[2][2] = {};
  const unsigned short* wsrc = Wcat + (size_t)cc0 * 512;
  const unsigned short* xsrc = Xlk + ((size_t)b * Lc + l0) * 512;
  int s_off[4], g_off[4];
#pragma unroll
  for (int r = 0; r < 4; ++r) {
    const int idx = r * 256 + tid;
    const int row = idx >> 3, ch = idx & 7;
    s_off[r] = row * 64 + (ch ^ (row & 7)) * 8;
    g_off[r] = row * 512 + ch * 8;
  }
  short8 ar[4], br[4];
#pragma unroll
  for (int r = 0; r < 4; ++r) {
    ar[r] = *(const short8*)(wsrc + g_off[r]);
    br[r] = *(const short8*)(xsrc + g_off[r]);
  }
  int cur = 0;
  for (int k0 = 0; k0 < 512; k0 += 64) {
#pragma unroll
    for (int r = 0; r < 4; ++r) {
      *(short8*)&As[cur][s_off[r]] = ar[r];
      *(short8*)&Bs[cur][s_off[r]] = br[r];
    }
    if (k0 + 64 < 512) {
#pragma unroll
      for (int r = 0; r < 4; ++r) {
        ar[r] = *(const short8*)(wsrc + g_off[r] + k0 + 64);
        br[r] = *(const short8*)(xsrc + g_off[r] + k0 + 64);
      }
    }
    __syncthreads();
#pragma unroll
    for (int s = 0; s < 4; ++s) {
      const int c = 2 * s + khalf;
      short8 af[2], bf[2];
#pragma unroll
      for (int i = 0; i < 2; ++i)
        af[i] = *(const short8*)&As[cur][(wcc + i * 32 + l31) * 64 + (c ^ (l31 & 7)) * 8];
#pragma unroll
      for (int j = 0; j < 2; ++j)
        bf[j] = *(const short8*)&Bs[cur][(wl + j * 32 + l31) * 64 + (c ^ (l31 & 7)) * 8];
#pragma unroll
      for (int i = 0; i < 2; ++i)
#pragma unroll
        for (int j = 0; j < 2; ++j)
          acc[i][j] = __builtin_amdgcn_mfma_f32_32x32x16_bf16(af[i], bf[j], acc[i][j], 0, 0, 0);
    }
    cur ^= 1;
  }
#pragma unroll
  for (int i = 0; i < 2; ++i) {
#pragma unroll
    for (int j = 0; j < 2; ++j) {
      const int l = l0 + wl + j * 32 + l31;
#pragma unroll
      for (int rg = 0; rg < 16; ++rg) {
        const int cc = cc0 + wcc + i * 32 + (rg & 3) + 8 * (rg >> 2) + 4 * khalf;
        vbf[((size_t)b * 512 + cc) * Lc + l] = f2bf(acc[i][j][rg]);
      }
    }
  }
}

// ---------------------------------------------------------------------------
// Phase 3: row max of E via MFMA QK^T, hi-only (approx max is sufficient).
// ---------------------------------------------------------------------------
__global__ __launch_bounds__(256) void e_max(const unsigned short* __restrict__ Qcat,
                                             const unsigned short* __restrict__ K1hi,
                                             const unsigned short* __restrict__ K2hi,
                                             float* __restrict__ Mrow) {
  const int tid  = threadIdx.x;
  const int w    = tid >> 6, lane = tid & 63;
  const int lrow = lane & 15, quad = lane >> 4, qsel = quad & 1;
  const int b    = blockIdx.z;
  const int m16  = blockIdx.x * 64 + w * 16;
  const int lbeg = blockIdx.y * 512;
  const size_t kb = (size_t)b * Lc;
  const short8 afrag = *(const short8*)(Qcat + (kb + m16 + lrow) * 32 + quad * 8);
  float mx[4] = {0.f, 0.f, 0.f, 0.f};
  for (int l0 = lbeg; l0 < lbeg + 512; l0 += 16) {
    const size_t l = kb + l0 + lrow;
    const short8 b1h = *(const short8*)(K1hi + l * 16 + qsel * 8);
    const short8 b2h = *(const short8*)(K2hi + l * 16 + qsel * 8);
    const floatx4 er = __builtin_amdgcn_mfma_f32_16x16x32_bf16(afrag, b1h, (floatx4){0.f, 0.f, 0.f, 0.f}, 0, 0, 0);
    const floatx4 ei = __builtin_amdgcn_mfma_f32_16x16x32_bf16(afrag, b2h, (floatx4){0.f, 0.f, 0.f, 0.f}, 0, 0, 0);
#pragma unroll
    for (int r = 0; r < 4; ++r) {
      float e = er[r] * er[r];
      e = fmaf(ei[r], ei[r], e);
      mx[r] = fmaxf(mx[r], e);
    }
  }
#pragma unroll
  for (int r = 0; r < 4; ++r) {
    float v = mx[r];
#pragma unroll
    for (int off = 1; off < 16; off <<= 1) v = fmaxf(v, __shfl_xor(v, off));
    if (lrow == 0)
      atomicMax((unsigned*)&Mrow[kb + m16 + quad * 4 + r], __float_as_uint(v));
  }
}

// ---------------------------------------------------------------------------
// Phase 4: att[m][l] = bf16(__expf(E-M)), refined split-bf16 E; row sums ->
// atomicAdd(Ssum).
// ---------------------------------------------------------------------------
__global__ __launch_bounds__(256) void e_exp(const unsigned short* __restrict__ Qcat,
                                             const unsigned short* __restrict__ K1hi,
                                             const unsigned short* __restrict__ K1lo,
                                             const unsigned short* __restrict__ K2hi,
                                             const unsigned short* __restrict__ K2lo,
                                             const float* __restrict__ Mrow,
                                             unsigned short* __restrict__ att,
                                             float* __restrict__ Ssum) {
  const int tid  = threadIdx.x;
  const int w    = tid >> 6, lane = tid & 63;
  const int lrow = lane & 15, quad = lane >> 4, qsel = quad & 1;
  const int b    = blockIdx.z;
  const int m16  = blockIdx.x * 64 + w * 16;
  const int lbeg = blockIdx.y * 512;
  const size_t kb = (size_t)b * Lc;
  const short8 afrag = *(const short8*)(Qcat + (kb + m16 + lrow) * 32 + quad * 8);
  float Mv[4], sum[4] = {};
#pragma unroll
  for (int r = 0; r < 4; ++r) Mv[r] = Mrow[kb + m16 + quad * 4 + r];
  for (int l0 = lbeg; l0 < lbeg + 512; l0 += 16) {
    const size_t l = kb + l0 + lrow;
    const short8 b1h = *(const short8*)(K1hi + l * 16 + qsel * 8);
    const short8 b1l = *(const short8*)(K1lo + l * 16 + qsel * 8);
    const short8 b2h = *(const short8*)(K2hi + l * 16 + qsel * 8);
    const short8 b2l = *(const short8*)(K2lo + l * 16 + qsel * 8);
    floatx4 er = __builtin_amdgcn_mfma_f32_16x16x32_bf16(afrag, b1l, (floatx4){0.f, 0.f, 0.f, 0.f}, 0, 0, 0);
    er = __builtin_amdgcn_mfma_f32_16x16x32_bf16(afrag, b1h, er, 0, 0, 0);
    floatx4 ei = __builtin_amdgcn_mfma_f32_16x16x32_bf16(afrag, b2l, (floatx4){0.f, 0.f, 0.f, 0.f}, 0, 0, 0);
    ei = __builtin_amdgcn_mfma_f32_16x16x32_bf16(afrag, b2h, ei, 0, 0, 0);
#pragma unroll
    for (int r = 0; r < 4; ++r) {
      float e = er[r] * er[r];
      e = fmaf(ei[r], ei[r], e);
      const float wgt = __expf(e - Mv[r]);
      sum[r] += wgt;
      att[(kb + m16 + quad * 4 + r) * Lc + l0 + lrow] = f2bf(wgt);
    }
  }
#pragma unroll
  for (int r = 0; r < 4; ++r) {
    float v = sum[r];
#pragma unroll
    for (int off = 1; off < 16; off <<= 1) v += __shfl_xor(v, off);
    if (lrow == 0) atomicAdd(&Ssum[kb + m16 + quad * 4 + r], v);
  }
}

// ---------------------------------------------------------------------------
// Phase 5: PV GEMM, 32x32x16 MFMA, 128cc x 128m tile, 64x64/wave (2x2 frags,
// 2-way LDS read sharing both operands), XOR swizzle, double-buffered LDS
// with a SINGLE barrier per k-iter (prev readers drained by previous barrier),
// register prefetch one full iteration deep.
// Epilogue: out = (gamma/Ssum[m]) * acc + x  (C: m=lane&31 -> 128B runs).
// ---------------------------------------------------------------------------
__global__ __launch_bounds__(256) void pv_gemm(const unsigned short* __restrict__ v,
                                               const unsigned short* __restrict__ att,
                                               const float* __restrict__ Ssum,
                                               const float* __restrict__ x,
                                               const float* __restrict__ gamma,
                                               float* __restrict__ out) {
  __shared__ short As[2][128 * 64];
  __shared__ short Bs[2][128 * 64];
  const int tid  = threadIdx.x;
  const int b    = blockIdx.z;
  const int cc0  = blockIdx.x * 128;
  const int m0   = blockIdx.y * 128;
  const int wid  = tid >> 6, lane = tid & 63;
  const int wcc  = (wid >> 1) * 64;
  const int wm   = (wid & 1) * 64;
  const int l31  = lane & 31, khalf = lane >> 5;
  floatx16 acc[2][2] = {};
  const unsigned short* vsrc = v   + ((size_t)b * 512 + cc0) * Lc;
  const unsigned short* asrc = att + ((size_t)b * Lc + m0) * Lc;
  int s_off[4];
  size_t g_off[4];
#pragma unroll
  for (int r = 0; r < 4; ++r) {
    const int idx = r * 256 + tid;
    const int row = idx >> 3, ch = idx & 7;
    s_off[r] = row * 64 + (ch ^ (row & 7)) * 8;
    g_off[r] = (size_t)row * Lc + ch * 8;
  }
  short8 ar[4], br[4];
#pragma unroll
  for (int r = 0; r < 4; ++r) {
    ar[r] = *(const short8*)(vsrc + g_off[r]);
    br[r] = *(const short8*)(asrc + g_off[r]);
  }
  int cur = 0;
  for (int k0 = 0; k0 < Lc; k0 += 64) {
#pragma unroll
    for (int r = 0; r < 4; ++r) {
      *(short8*)&As[cur][s_off[r]] = ar[r];
      *(short8*)&Bs[cur][s_off[r]] = br[r];
    }
    if (k0 + 64 < Lc) {
#pragma unroll
      for (int r = 0; r < 4; ++r) {
        ar[r] = *(const short8*)(vsrc + g_off[r] + k0 + 64);
        br[r] = *(const short8*)(asrc + g_off[r] + k0 + 64);
      }
    }
    __syncthreads();
#pragma unroll
    for (int s = 0; s < 4; ++s) {
      const int c = 2 * s + khalf;
      short8 af[2], bf[2];
#pragma unroll
      for (int i = 0; i < 2; ++i)
        af[i] = *(const short8*)&As[cur][(wcc + i * 32 + l31) * 64 + (c ^ (l31 & 7)) * 8];
#pragma unroll
      for (int j = 0; j < 2; ++j)
        bf[j] = *(const short8*)&Bs[cur][(wm + j * 32 + l31) * 64 + (c ^ (l31 & 7)) * 8];
#pragma unroll
      for (int i = 0; i < 2; ++i)
#pragma unroll
        for (int j = 0; j < 2; ++j)
          acc[i][j] = __builtin_amdgcn_mfma_f32_32x32x16_bf16(af[i], bf[j], acc[i][j], 0, 0, 0);
    }
    cur ^= 1;
  }
  const float gm = gamma[0];
  float sv[2];
#pragma unroll
  for (int j = 0; j < 2; ++j)
    sv[j] = gm / Ssum[(size_t)b * Lc + m0 + wm + j * 32 + l31];
#pragma unroll
  for (int i = 0; i < 2; ++i) {
#pragma unroll
    for (int j = 0; j < 2; ++j) {
      const int m = m0 + wm + j * 32 + l31;
#pragma unroll
      for (int rg = 0; rg < 16; ++rg) {
        const int cc   = cc0 + wcc + i * 32 + (rg & 3) + 8 * (rg >> 2) + 4 * khalf;
        const int comp = cc >> 8, c = cc & 255;
        const size_t idx = (((size_t)comp * Bc + b) * CGc + c) * Lc + m;
        out[idx] = sv[j] * acc[i][j][rg] + x[idx];
      }
    }
  }
}

// ---------------------------------------------------------------------------
extern "C" void kernel_launch(void* const* d_in, const int* in_sizes, int n_in,
                              void* d_out, int out_size, void* d_ws, size_t ws_size,
                              hipStream_t stream) {
  const float* x     = (const float*)d_in[0];
  const float* wq    = (const float*)d_in[1];
  const float* wk    = (const float*)d_in[2];
  const float* wv    = (const float*)d_in[3];
  const float* gamma = (const float*)d_in[4];
  float* out = (float*)d_out;

  // Workspace (~78.7 MB). Xlk aliases att (stream-ordered: v_gemm reads Xlk
  // before e_exp overwrites the region with att).
  float* q    = (float*)d_ws;                         // 131072
  float* kk   = q    + (size_t)Bc * Lc * 16;          // 131072
  float* Mrow = kk   + (size_t)Bc * Lc * 16;          // 8192  } contiguous:
  float* Ssum = Mrow + (size_t)Bc * Lc;               // 8192  } init zeroes both
  unsigned short* vbf  = (unsigned short*)(Ssum + (size_t)Bc * Lc);  // 2*512*4096
  unsigned short* att  = vbf + (size_t)Bc * 512 * Lc;                // 2*4096*4096
  unsigned short* Xlk  = att;                                        // alias (8.4MB)
  unsigned short* Qcat = att + (size_t)Bc * Lc * Lc;                 // 8192*32
  unsigned short* K1hi = Qcat + (size_t)Bc * Lc * 32;                // 8192*16
  unsigned short* K1lo = K1hi + (size_t)Bc * Lc * 16;
  unsigned short* K2hi = K1lo + (size_t)Bc * Lc * 16;
  unsigned short* K2lo = K2hi + (size_t)Bc * Lc * 16;
  unsigned short* Wcat = K2lo + (size_t)Bc * Lc * 16;                // 512*512

  init_stats<<<dim3((2 * Bc * Lc) / 256), 256, 0, stream>>>(Mrow);
  wcat_pack<<<dim3((512 * 512) / 256), 256, 0, stream>>>(wv, Wcat);
  qk_proj<<<dim3(Lc / 32, Bc), 256, 0, stream>>>(x, wq, wk, q, kk);
  qk_pack<<<dim3((Bc * Lc) / 256), 256, 0, stream>>>(q, kk, Qcat, K1hi, K1lo, K2hi, K2lo);
  xT_pack<<<dim3(Lc / 64, 8, Bc), 256, 0, stream>>>(x, Xlk);
  v_gemm<<<dim3(512 / 128, Lc / 128, Bc), 256, 0, stream>>>(Wcat, Xlk, vbf);
  e_max<<<dim3(Lc / 64, 8, Bc), 256, 0, stream>>>(Qcat, K1hi, K2hi, Mrow);
  e_exp<<<dim3(Lc / 64, 8, Bc), 256, 0, stream>>>(Qcat, K1hi, K1lo, K2hi, K2lo, Mrow, att, Ssum);
  pv_gemm<<<dim3(512 / 128, Lc / 128, Bc), 256, 0, stream>>>(vbf, att, Ssum, x, gamma, out);
}